// Round 1
// baseline (321.210 us; speedup 1.0000x reference)
//
#include <hip/hip_runtime.h>
#include <hip/hip_bf16.h>
#include <stdint.h>

typedef unsigned short u16;
typedef __attribute__((ext_vector_type(8))) short bf16x8;
typedef __attribute__((ext_vector_type(4))) float f32x4;

#define T_SEQ 2048

__device__ __forceinline__ float bf2f(u16 u) {
  union { uint32_t i; float f; } v; v.i = ((uint32_t)u) << 16; return v.f;
}
__device__ __forceinline__ u16 f2bf(float f) {
  union { float f; uint32_t i; } v; v.f = f;
  uint32_t u = v.i;
  return (u16)((u + 0x7fffu + ((u >> 16) & 1u)) >> 16);
}

__device__ __forceinline__ void gload_lds16(const void* g, void* l) {
  __builtin_amdgcn_global_load_lds(
      (const __attribute__((address_space(1))) void*)g,
      (__attribute__((address_space(3))) void*)l, 16, 0, 0);
}

// ---------------- fp32 -> bf16 convert ----------------
__global__ __launch_bounds__(256) void cvt_kernel(const float* __restrict__ src,
                                                  u16* __restrict__ dst, int n) {
  int i = (blockIdx.x * 256 + threadIdx.x) * 4;
  if (i + 3 < n) {
    const float4 v = *(const float4*)(src + i);
    ushort4 o;
    o.x = f2bf(v.x); o.y = f2bf(v.y); o.z = f2bf(v.z); o.w = f2bf(v.w);
    *(ushort4*)(dst + i) = o;
  }
}

// ---------------- GEMM core: C[128x64] += A[128xK] * B[64xK]^T, K=1024 ----
// A rows K-contiguous, B rows (= output cols) K-contiguous.
// LDS tiles staged via global_load_lds with pre-swizzled global source:
// element (row, colbyte) lives at lds byte row*128 + (colbyte ^ ((row&7)<<4)).
__device__ __forceinline__ void gemm_core_128x64(
    f32x4 acc[2][4], const u16* __restrict__ A, const u16* __restrict__ Bw,
    int bm, int bn, u16* As, u16* Bs)
{
  const int tid = threadIdx.x;
  const int w = tid >> 6, lane = tid & 63, g = lane >> 4, c = lane & 15;
  for (int k0 = 0; k0 < 1024; k0 += 64) {
    __syncthreads();
    // stage A tile: 128 rows x 64 k (16 KB) = 16 wave-issues
    #pragma unroll
    for (int is = 0; is < 4; ++is) {
      int o = (is*4 + w)*1024 + lane*16;
      int row = o >> 7, c16 = (o >> 4) & 7;
      gload_lds16(A + (size_t)(bm*128 + row)*1024 + k0 + (c16 ^ (row & 7))*8,
                  (char*)As + (is*4 + w)*1024);
    }
    // stage B tile: 64 rows x 64 k (8 KB) = 8 wave-issues
    #pragma unroll
    for (int is = 0; is < 2; ++is) {
      int o = (is*4 + w)*1024 + lane*16;
      int row = o >> 7, c16 = (o >> 4) & 7;
      gload_lds16(Bw + (size_t)(bn*64 + row)*1024 + k0 + (c16 ^ (row & 7))*8,
                  (char*)Bs + (is*4 + w)*1024);
    }
    __syncthreads();
    bf16x8 af[2][2], bfr[4][2];
    #pragma unroll
    for (int mf = 0; mf < 2; ++mf)
      #pragma unroll
      for (int kc = 0; kc < 2; ++kc) {
        int row = w*32 + mf*16 + c;
        int colb = kc*64 + g*16;
        af[mf][kc] = *(const bf16x8*)((const char*)As + row*128 + (colb ^ ((row & 7) << 4)));
      }
    #pragma unroll
    for (int nf = 0; nf < 4; ++nf)
      #pragma unroll
      for (int kc = 0; kc < 2; ++kc) {
        int row = nf*16 + c;
        int colb = kc*64 + g*16;
        bfr[nf][kc] = *(const bf16x8*)((const char*)Bs + row*128 + (colb ^ ((row & 7) << 4)));
      }
    #pragma unroll
    for (int mf = 0; mf < 2; ++mf)
      #pragma unroll
      for (int nf = 0; nf < 4; ++nf)
        #pragma unroll
        for (int kc = 0; kc < 2; ++kc)
          acc[mf][nf] = __builtin_amdgcn_mfma_f32_16x16x32_bf16(
              af[mf][kc], bfr[nf][kc], acc[mf][nf], 0, 0, 0);
  }
}

// ---------------- QKV projection ----------------
// out(z=0): Q = (x Wq^T + bq) * 0.125 ; z=1: K ; z=2: V. Stored [B*H][T][64] bf16.
__global__ __launch_bounds__(256, 2) void gemm_qkv(
    const u16* __restrict__ Abf, const u16* __restrict__ Wbf,
    const float* __restrict__ bq, const float* __restrict__ bk,
    const float* __restrict__ bv, u16* __restrict__ qkvh)
{
  __shared__ __align__(16) u16 As[128*64];
  __shared__ __align__(16) u16 Bs[64*64];
  f32x4 acc[2][4];
  #pragma unroll
  for (int mf = 0; mf < 2; ++mf)
    #pragma unroll
    for (int nf = 0; nf < 4; ++nf) acc[mf][nf] = (f32x4){0.f,0.f,0.f,0.f};
  const int z = blockIdx.z;
  gemm_core_128x64(acc, Abf, Wbf + (size_t)z*1048576, blockIdx.x, blockIdx.y, As, Bs);
  const float* bias = (z == 0) ? bq : (z == 1) ? bk : bv;
  const float scl = (z == 0) ? 0.125f : 1.0f;
  u16* dst = qkvh + (size_t)z * 4194304;
  const int tid = threadIdx.x, w = tid >> 6, lane = tid & 63, g = lane >> 4, c = lane & 15;
  #pragma unroll
  for (int mf = 0; mf < 2; ++mf)
    #pragma unroll
    for (int nf = 0; nf < 4; ++nf) {
      int col = blockIdx.y*64 + nf*16 + c;
      float bcol = bias[col];
      int h = col >> 6, d = col & 63;
      #pragma unroll
      for (int r = 0; r < 4; ++r) {
        int row = blockIdx.x*128 + w*32 + mf*16 + g*4 + r;
        int t = row >> 1, bb = row & 1;
        float v = (acc[mf][nf][r] + bcol) * scl;
        dst[(size_t)(bb*16 + h)*131072 + (size_t)t*64 + d] = f2bf(v);
      }
    }
}

// ---------------- output projection: out = ctx2 Wo^T + bo (fp32) ----------
__global__ __launch_bounds__(256, 2) void gemm_out(
    const u16* __restrict__ ctx2, const u16* __restrict__ Wobf,
    const float* __restrict__ bo, float* __restrict__ out)
{
  __shared__ __align__(16) u16 As[128*64];
  __shared__ __align__(16) u16 Bs[64*64];
  f32x4 acc[2][4];
  #pragma unroll
  for (int mf = 0; mf < 2; ++mf)
    #pragma unroll
    for (int nf = 0; nf < 4; ++nf) acc[mf][nf] = (f32x4){0.f,0.f,0.f,0.f};
  gemm_core_128x64(acc, ctx2, Wobf, blockIdx.x, blockIdx.y, As, Bs);
  const int tid = threadIdx.x, w = tid >> 6, lane = tid & 63, g = lane >> 4, c = lane & 15;
  #pragma unroll
  for (int mf = 0; mf < 2; ++mf)
    #pragma unroll
    for (int nf = 0; nf < 4; ++nf) {
      int col = blockIdx.y*64 + nf*16 + c;
      float bcol = bo[col];
      #pragma unroll
      for (int r = 0; r < 4; ++r) {
        int row = blockIdx.x*128 + w*32 + mf*16 + g*4 + r;
        out[(size_t)row*1024 + col] = acc[mf][nf][r] + bcol;
      }
    }
}

// ---------------- V column sums (edge-case fallback) ----------------
__global__ __launch_bounds__(256) void vsum_kernel(const u16* __restrict__ Vh,
                                                   float* __restrict__ vs) {
  __shared__ float red[256];
  int bh = blockIdx.x, tid = threadIdx.x;
  int d = tid & 63, tc = tid >> 6;
  const u16* p = Vh + (size_t)bh*131072 + d;
  float s = 0.f;
  for (int t = tc; t < 2048; t += 4) s += bf2f(p[(size_t)t*64]);
  red[tid] = s;
  __syncthreads();
  if (tid < 64) vs[bh*64 + d] = red[d] + red[64+d] + red[128+d] + red[192+d];
}

// ---------------- flash attention ----------------
// grid (16 q-tiles, 32 bh). 4 waves x 32 q-rows, KVBLK=64, online softmax.
// Fully-masked row (l==0): reference softmax over an all-NEG row is uniform
// 1/T over ALL keys -> output Vsum/2048.
__global__ __launch_bounds__(256, 2) void flash_attn(
    const u16* __restrict__ Qh, const u16* __restrict__ Kh,
    const u16* __restrict__ Vh, const int* __restrict__ kpm,
    const float* __restrict__ vsum, u16* __restrict__ ctx2)
{
  __shared__ __align__(16) u16 Kl[64*64];
  __shared__ __align__(16) u16 VT[64*64];      // [d][s] swizzled
  __shared__ __align__(16) u16 Pl[4][32*64];   // per-wave P, swizzled
  __shared__ int pml[64];

  const int tid = threadIdx.x, w = tid >> 6, lane = tid & 63;
  const int g = lane >> 4, c = lane & 15;
  const int bh = blockIdx.y, b = bh >> 4, h = bh & 15;
  const int q0 = blockIdx.x * 128;
  const size_t hb = (size_t)bh * 131072;

  bf16x8 qf[2][2];
  #pragma unroll
  for (int mf = 0; mf < 2; ++mf)
    #pragma unroll
    for (int kc = 0; kc < 2; ++kc) {
      int qr = q0 + w*32 + mf*16 + c;
      qf[mf][kc] = *(const bf16x8*)(Qh + hb + (size_t)qr*64 + kc*32 + g*8);
    }

  float mrow[2][4], lrow[2][4];
  f32x4 cacc[2][4];
  #pragma unroll
  for (int mf = 0; mf < 2; ++mf) {
    #pragma unroll
    for (int r = 0; r < 4; ++r) { mrow[mf][r] = -__builtin_inff(); lrow[mf][r] = 0.f; }
    #pragma unroll
    for (int dt = 0; dt < 4; ++dt) cacc[mf][dt] = (f32x4){0.f,0.f,0.f,0.f};
  }

  const int send = q0 + 128;
  for (int s0 = 0; s0 < send; s0 += 64) {
    __syncthreads();
    // stage K tile (swizzled source -> linear LDS -> swizzled read)
    #pragma unroll
    for (int is = 0; is < 2; ++is) {
      int o = (is*4 + w)*1024 + lane*16;
      int row = o >> 7, c16 = (o >> 4) & 7;
      gload_lds16(Kh + hb + (size_t)(s0 + row)*64 + (c16 ^ (row & 7))*8,
                  (char*)Kl + (is*4 + w)*1024);
    }
    // stage V transposed: VT[d][s], XOR-swizzled rows
    {
      int s = tid >> 2, d0 = (tid & 3) * 16;
      const u16* vp = Vh + hb + (size_t)(s0 + s)*64 + d0;
      bf16x8 v0 = *(const bf16x8*)vp;
      bf16x8 v1 = *(const bf16x8*)(vp + 8);
      #pragma unroll
      for (int j = 0; j < 8; ++j) {
        int da = d0 + j, db = d0 + 8 + j;
        *(u16*)((char*)VT + da*128 + ((2*s) ^ ((da & 7) << 4))) = (u16)v0[j];
        *(u16*)((char*)VT + db*128 + ((2*s) ^ ((db & 7) << 4))) = (u16)v1[j];
      }
    }
    if (tid < 64) pml[tid] = kpm[b*T_SEQ + s0 + tid];
    __syncthreads();

    // S = Q K^T  (S[32 q][64 kv] per wave)
    f32x4 sacc[2][4];
    #pragma unroll
    for (int mf = 0; mf < 2; ++mf)
      #pragma unroll
      for (int nf = 0; nf < 4; ++nf) sacc[mf][nf] = (f32x4){0.f,0.f,0.f,0.f};
    {
      bf16x8 kf[4][2];
      #pragma unroll
      for (int nf = 0; nf < 4; ++nf)
        #pragma unroll
        for (int kc = 0; kc < 2; ++kc) {
          int row = nf*16 + c;
          int colb = kc*64 + g*16;
          kf[nf][kc] = *(const bf16x8*)((const char*)Kl + row*128 + (colb ^ ((row & 7) << 4)));
        }
      #pragma unroll
      for (int mf = 0; mf < 2; ++mf)
        #pragma unroll
        for (int nf = 0; nf < 4; ++nf)
          #pragma unroll
          for (int kc = 0; kc < 2; ++kc)
            sacc[mf][nf] = __builtin_amdgcn_mfma_f32_16x16x32_bf16(
                qf[mf][kc], kf[nf][kc], sacc[mf][nf], 0, 0, 0);
    }

    int pmv[4];
    #pragma unroll
    for (int nf = 0; nf < 4; ++nf) pmv[nf] = pml[nf*16 + c];

    // online softmax, write P to per-wave LDS
    #pragma unroll
    for (int mf = 0; mf < 2; ++mf) {
      const int qb = q0 + w*32 + mf*16 + g*4;
      float sv[4][4];
      #pragma unroll
      for (int nf = 0; nf < 4; ++nf) {
        const int kv = s0 + nf*16 + c;
        #pragma unroll
        for (int r = 0; r < 4; ++r) {
          float x = sacc[mf][nf][r];
          sv[nf][r] = ((kv > qb + r) || pmv[nf]) ? -__builtin_inff() : x;
        }
      }
      #pragma unroll
      for (int r = 0; r < 4; ++r) {
        float rm = fmaxf(fmaxf(sv[0][r], sv[1][r]), fmaxf(sv[2][r], sv[3][r]));
        #pragma unroll
        for (int off = 1; off < 16; off <<= 1) rm = fmaxf(rm, __shfl_xor(rm, off, 64));
        const float mo = mrow[mf][r];
        const float mn = fmaxf(mo, rm);
        const bool deadrow = (mn == -__builtin_inff());
        const float sc = deadrow ? 1.0f : __expf(mo - mn);
        mrow[mf][r] = mn;
        float ps = 0.f;
        u16 pb[4];
        #pragma unroll
        for (int nf = 0; nf < 4; ++nf) {
          float p = deadrow ? 0.f : __expf(sv[nf][r] - mn);
          ps += p;
          pb[nf] = f2bf(p);
        }
        #pragma unroll
        for (int off = 1; off < 16; off <<= 1) ps += __shfl_xor(ps, off, 64);
        lrow[mf][r] = lrow[mf][r] * sc + ps;
        #pragma unroll
        for (int dt = 0; dt < 4; ++dt) cacc[mf][dt][r] *= sc;
        const int prow = mf*16 + g*4 + r;
        #pragma unroll
        for (int nf = 0; nf < 4; ++nf)
          *(u16*)((char*)Pl[w] + prow*128 + ((nf*32 + 2*c) ^ ((prow & 7) << 4))) = pb[nf];
      }
    }

    // ctx += P V
    {
      bf16x8 pf[2][2], vf2[4][2];
      #pragma unroll
      for (int mf = 0; mf < 2; ++mf)
        #pragma unroll
        for (int sc2 = 0; sc2 < 2; ++sc2) {
          int row = mf*16 + c;
          int colb = sc2*64 + g*16;
          pf[mf][sc2] = *(const bf16x8*)((const char*)Pl[w] + row*128 + (colb ^ ((row & 7) << 4)));
        }
      #pragma unroll
      for (int dt = 0; dt < 4; ++dt)
        #pragma unroll
        for (int sc2 = 0; sc2 < 2; ++sc2) {
          int row = dt*16 + c;
          int colb = sc2*64 + g*16;
          vf2[dt][sc2] = *(const bf16x8*)((const char*)VT + row*128 + (colb ^ ((row & 7) << 4)));
        }
      #pragma unroll
      for (int mf = 0; mf < 2; ++mf)
        #pragma unroll
        for (int dt = 0; dt < 4; ++dt)
          #pragma unroll
          for (int sc2 = 0; sc2 < 2; ++sc2)
            cacc[mf][dt] = __builtin_amdgcn_mfma_f32_16x16x32_bf16(
                pf[mf][sc2], vf2[dt][sc2], cacc[mf][dt], 0, 0, 0);
    }
  }

  // epilogue: ctx2[(t*B+b)][h*64+d] bf16
  #pragma unroll
  for (int mf = 0; mf < 2; ++mf)
    #pragma unroll
    for (int r = 0; r < 4; ++r) {
      const int q = q0 + w*32 + mf*16 + g*4 + r;
      const float l = lrow[mf][r];
      const bool dead = (l == 0.f);
      const float rl = dead ? 0.f : 1.0f / l;
      #pragma unroll
      for (int dt = 0; dt < 4; ++dt) {
        const int d = dt*16 + c;
        float v = dead ? vsum[bh*64 + d] * (1.0f/2048.0f) : cacc[mf][dt][r] * rl;
        ctx2[(size_t)(q*2 + b)*1024 + (size_t)h*64 + d] = f2bf(v);
      }
    }
}

extern "C" void kernel_launch(void* const* d_in, const int* in_sizes, int n_in,
                              void* d_out, int out_size, void* d_ws, size_t ws_size,
                              hipStream_t stream) {
  const float* query = (const float*)d_in[0];
  const int*   kpm   = (const int*)d_in[1];
  // d_in[2] attn_mask: unused (causal semantics implemented directly)
  const float* Wq = (const float*)d_in[3];
  const float* bq = (const float*)d_in[4];
  const float* Wk = (const float*)d_in[5];
  const float* bk = (const float*)d_in[6];
  const float* Wv = (const float*)d_in[7];
  const float* bv = (const float*)d_in[8];
  const float* Wo = (const float*)d_in[9];
  const float* bo = (const float*)d_in[10];

  char* ws = (char*)d_ws;
  u16*   qbf  = (u16*)(ws);                  // 4194304 elems (query bf16, [4096][1024])
  u16*   wbf  = (u16*)(ws + 8388608);        // 4 x 1048576 (Wq,Wk,Wv,Wo bf16)
  u16*   qkvh = (u16*)(ws + 16777216);       // 3 x 4194304 (Q,K,V head-major bf16)
  u16*   ctx2 = (u16*)(ws + 41943040);       // 4194304 ([T*B][E] bf16)
  float* vsum = (float*)(ws + 50331648);     // 2048 floats

  cvt_kernel<<<dim3(4096), 256, 0, stream>>>(query, qbf, 4194304);
  cvt_kernel<<<dim3(1024), 256, 0, stream>>>(Wq, wbf + 0*1048576, 1048576);
  cvt_kernel<<<dim3(1024), 256, 0, stream>>>(Wk, wbf + 1*1048576, 1048576);
  cvt_kernel<<<dim3(1024), 256, 0, stream>>>(Wv, wbf + 2*1048576, 1048576);
  cvt_kernel<<<dim3(1024), 256, 0, stream>>>(Wo, wbf + 3*1048576, 1048576);

  gemm_qkv<<<dim3(32, 16, 3), 256, 0, stream>>>(qbf, wbf, bq, bk, bv, qkvh);
  vsum_kernel<<<dim3(32), 256, 0, stream>>>(qkvh + 2*4194304, vsum);
  flash_attn<<<dim3(16, 32), 256, 0, stream>>>(qkvh, qkvh + 1*4194304,
                                               qkvh + 2*4194304, kpm, vsum, ctx2);
  gemm_out<<<dim3(32, 16), 256, 0, stream>>>(ctx2, wbf + 3*1048576, bo, (float*)d_out);
}

// Round 2
// 174.565 us; speedup vs baseline: 1.8401x; 1.8401x over previous
//
#include <hip/hip_runtime.h>
#include <hip/hip_bf16.h>
#include <stdint.h>

typedef unsigned short u16;
typedef __attribute__((ext_vector_type(8))) short bf16x8;
typedef __attribute__((ext_vector_type(4))) float f32x4;

#define T_SEQ 2048

__device__ __forceinline__ float bf2f(u16 u) {
  union { uint32_t i; float f; } v; v.i = ((uint32_t)u) << 16; return v.f;
}
__device__ __forceinline__ u16 f2bf(float f) {
  union { float f; uint32_t i; } v; v.f = f;
  uint32_t u = v.i;
  return (u16)((u + 0x7fffu + ((u >> 16) & 1u)) >> 16);
}

__device__ __forceinline__ void gload_lds16(const void* g, void* l) {
  __builtin_amdgcn_global_load_lds(
      (const __attribute__((address_space(1))) void*)g,
      (__attribute__((address_space(3))) void*)l, 16, 0, 0);
}

// ---------------- fp32 -> bf16 converts ----------------
__global__ __launch_bounds__(256) void cvt_kernel(const float* __restrict__ src,
                                                  u16* __restrict__ dst, int n) {
  int i = (blockIdx.x * 256 + threadIdx.x) * 4;
  if (i + 3 < n) {
    const float4 v = *(const float4*)(src + i);
    ushort4 o;
    o.x = f2bf(v.x); o.y = f2bf(v.y); o.z = f2bf(v.z); o.w = f2bf(v.w);
    *(ushort4*)(dst + i) = o;
  }
}

__global__ __launch_bounds__(256) void cvt4_kernel(
    const float* __restrict__ s0, const float* __restrict__ s1,
    const float* __restrict__ s2, const float* __restrict__ s3,
    u16* __restrict__ dst) {
  const int z = blockIdx.y;
  const float* src = (z == 0) ? s0 : (z == 1) ? s1 : (z == 2) ? s2 : s3;
  int i = (blockIdx.x * 256 + threadIdx.x) * 4;
  const float4 v = *(const float4*)(src + i);
  ushort4 o;
  o.x = f2bf(v.x); o.y = f2bf(v.y); o.z = f2bf(v.z); o.w = f2bf(v.w);
  *(ushort4*)(dst + (size_t)z * 1048576 + i) = o;
}

// ---------------- GEMM core: C[128x64] += A[128xK] * B[64xK]^T, K=1024 ----
__device__ __forceinline__ void gemm_core_128x64(
    f32x4 acc[2][4], const u16* __restrict__ A, const u16* __restrict__ Bw,
    int bm, int bn, u16* As, u16* Bs)
{
  const int tid = threadIdx.x;
  const int w = tid >> 6, lane = tid & 63, g = lane >> 4, c = lane & 15;
  for (int k0 = 0; k0 < 1024; k0 += 64) {
    __syncthreads();
    #pragma unroll
    for (int is = 0; is < 4; ++is) {
      int o = (is*4 + w)*1024 + lane*16;
      int row = o >> 7, c16 = (o >> 4) & 7;
      gload_lds16(A + (size_t)(bm*128 + row)*1024 + k0 + (c16 ^ (row & 7))*8,
                  (char*)As + (is*4 + w)*1024);
    }
    #pragma unroll
    for (int is = 0; is < 2; ++is) {
      int o = (is*4 + w)*1024 + lane*16;
      int row = o >> 7, c16 = (o >> 4) & 7;
      gload_lds16(Bw + (size_t)(bn*64 + row)*1024 + k0 + (c16 ^ (row & 7))*8,
                  (char*)Bs + (is*4 + w)*1024);
    }
    __syncthreads();
    bf16x8 af[2][2], bfr[4][2];
    #pragma unroll
    for (int mf = 0; mf < 2; ++mf)
      #pragma unroll
      for (int kc = 0; kc < 2; ++kc) {
        int row = w*32 + mf*16 + c;
        int colb = kc*64 + g*16;
        af[mf][kc] = *(const bf16x8*)((const char*)As + row*128 + (colb ^ ((row & 7) << 4)));
      }
    #pragma unroll
    for (int nf = 0; nf < 4; ++nf)
      #pragma unroll
      for (int kc = 0; kc < 2; ++kc) {
        int row = nf*16 + c;
        int colb = kc*64 + g*16;
        bfr[nf][kc] = *(const bf16x8*)((const char*)Bs + row*128 + (colb ^ ((row & 7) << 4)));
      }
    #pragma unroll
    for (int mf = 0; mf < 2; ++mf)
      #pragma unroll
      for (int nf = 0; nf < 4; ++nf)
        #pragma unroll
        for (int kc = 0; kc < 2; ++kc)
          acc[mf][nf] = __builtin_amdgcn_mfma_f32_16x16x32_bf16(
              af[mf][kc], bfr[nf][kc], acc[mf][nf], 0, 0, 0);
  }
}

// ---------------- QKV projection ----------------
__global__ __launch_bounds__(256, 2) void gemm_qkv(
    const u16* __restrict__ Abf, const u16* __restrict__ Wbf,
    const float* __restrict__ bq, const float* __restrict__ bk,
    const float* __restrict__ bv, u16* __restrict__ qkvh)
{
  __shared__ __align__(16) u16 As[128*64];
  __shared__ __align__(16) u16 Bs[64*64];
  f32x4 acc[2][4];
  #pragma unroll
  for (int mf = 0; mf < 2; ++mf)
    #pragma unroll
    for (int nf = 0; nf < 4; ++nf) acc[mf][nf] = (f32x4){0.f,0.f,0.f,0.f};
  const int z = blockIdx.z;
  gemm_core_128x64(acc, Abf, Wbf + (size_t)z*1048576, blockIdx.x, blockIdx.y, As, Bs);
  const float* bias = (z == 0) ? bq : (z == 1) ? bk : bv;
  const float scl = (z == 0) ? 0.125f : 1.0f;
  u16* dst = qkvh + (size_t)z * 4194304;
  const int tid = threadIdx.x, w = tid >> 6, lane = tid & 63, g = lane >> 4, c = lane & 15;
  #pragma unroll
  for (int mf = 0; mf < 2; ++mf)
    #pragma unroll
    for (int nf = 0; nf < 4; ++nf) {
      int col = blockIdx.y*64 + nf*16 + c;
      float bcol = bias[col];
      int h = col >> 6, d = col & 63;
      #pragma unroll
      for (int r = 0; r < 4; ++r) {
        int row = blockIdx.x*128 + w*32 + mf*16 + g*4 + r;
        int t = row >> 1, bb = row & 1;
        float v = (acc[mf][nf][r] + bcol) * scl;
        dst[(size_t)(bb*16 + h)*131072 + (size_t)t*64 + d] = f2bf(v);
      }
    }
}

// ---------------- output projection ----------------
__global__ __launch_bounds__(256, 2) void gemm_out(
    const u16* __restrict__ ctx2, const u16* __restrict__ Wobf,
    const float* __restrict__ bo, float* __restrict__ out)
{
  __shared__ __align__(16) u16 As[128*64];
  __shared__ __align__(16) u16 Bs[64*64];
  f32x4 acc[2][4];
  #pragma unroll
  for (int mf = 0; mf < 2; ++mf)
    #pragma unroll
    for (int nf = 0; nf < 4; ++nf) acc[mf][nf] = (f32x4){0.f,0.f,0.f,0.f};
  gemm_core_128x64(acc, ctx2, Wobf, blockIdx.x, blockIdx.y, As, Bs);
  const int tid = threadIdx.x, w = tid >> 6, lane = tid & 63, g = lane >> 4, c = lane & 15;
  #pragma unroll
  for (int mf = 0; mf < 2; ++mf)
    #pragma unroll
    for (int nf = 0; nf < 4; ++nf) {
      int col = blockIdx.y*64 + nf*16 + c;
      float bcol = bo[col];
      #pragma unroll
      for (int r = 0; r < 4; ++r) {
        int row = blockIdx.x*128 + w*32 + mf*16 + g*4 + r;
        out[(size_t)row*1024 + col] = acc[mf][nf][r] + bcol;
      }
    }
}

// ---------------- V column sums (parallel, atomic) ----------------
// grid 256 = 32 bh x 8 t-chunks. vs must be pre-zeroed.
__global__ __launch_bounds__(256) void vsum_kernel(const u16* __restrict__ Vh,
                                                   float* __restrict__ vs) {
  __shared__ float red[256][8];
  const int bh = blockIdx.x >> 3, ch = blockIdx.x & 7;
  const int tid = threadIdx.x;
  const int r0 = (tid >> 3), d0 = (tid & 7) * 8;
  const u16* p = Vh + (size_t)bh*131072 + (size_t)(ch*256 + r0)*64 + d0;
  float acc[8];
  #pragma unroll
  for (int j = 0; j < 8; ++j) acc[j] = 0.f;
  #pragma unroll
  for (int it = 0; it < 8; ++it) {
    bf16x8 v = *(const bf16x8*)(p + (size_t)it*32*64);
    #pragma unroll
    for (int j = 0; j < 8; ++j) acc[j] += bf2f((u16)v[j]);
  }
  #pragma unroll
  for (int j = 0; j < 8; ++j) red[tid][j] = acc[j];
  __syncthreads();
  if (tid < 64) {
    const int dg = tid >> 3, j = tid & 7;
    float s = 0.f;
    #pragma unroll
    for (int k = 0; k < 32; ++k) s += red[dg + 8*k][j];
    atomicAdd(&vs[bh*64 + dg*8 + j], s);
  }
}

// ---------------- flash attention ----------------
// Flat grid 512; ids 0..255 -> heavy tiles qt=15-pr, 256..511 -> qt=pr.
// Single-barrier 2-phase pipeline: prefetch (Vregs, kpm reg, K->LDS) for t+1,
// compute tile t, write VT[t+1], drain, one s_barrier.
__global__ __launch_bounds__(256, 2) void flash_attn(
    const u16* __restrict__ Qh, const u16* __restrict__ Kh,
    const u16* __restrict__ Vh, const int* __restrict__ kpm,
    const float* __restrict__ vsum, u16* __restrict__ ctx2)
{
  __shared__ __align__(16) u16 Kl[2][64*64];
  __shared__ __align__(16) u16 VT[2][64*64];
  __shared__ __align__(16) u16 Pl[4][32*64];

  const int tid = threadIdx.x, w = tid >> 6, lane = tid & 63;
  const int g = lane >> 4, c = lane & 15;
  const int id = blockIdx.x;
  const int u = id & 255, hi2 = id >> 8;
  const int bh = u & 31, pr = u >> 5;
  const int qt = hi2 ? pr : (15 - pr);
  const int b = bh >> 4, h = bh & 15;
  const int q0 = qt * 128;
  const size_t hb = (size_t)bh * 131072;
  const int nt = 2*qt + 2;

  bf16x8 qf[2][2];
  #pragma unroll
  for (int mf = 0; mf < 2; ++mf)
    #pragma unroll
    for (int kc = 0; kc < 2; ++kc) {
      int qr = q0 + w*32 + mf*16 + c;
      qf[mf][kc] = *(const bf16x8*)(Qh + hb + (size_t)qr*64 + kc*32 + g*8);
    }

  float mrow[2][4], lrow[2][4];
  f32x4 cacc[2][4];
  #pragma unroll
  for (int mf = 0; mf < 2; ++mf) {
    #pragma unroll
    for (int r = 0; r < 4; ++r) { mrow[mf][r] = -__builtin_inff(); lrow[mf][r] = 0.f; }
    #pragma unroll
    for (int dt = 0; dt < 4; ++dt) cacc[mf][dt] = (f32x4){0.f,0.f,0.f,0.f};
  }

  const int vs_s = tid >> 2, vs_d0 = (tid & 3) * 16;
  bf16x8 vreg0, vreg1;
  int kpmreg;

  // ---- prologue: stage tile 0 ----
  {
    const u16* vp = Vh + hb + (size_t)vs_s*64 + vs_d0;
    vreg0 = *(const bf16x8*)vp;
    vreg1 = *(const bf16x8*)(vp + 8);
    kpmreg = kpm[b*T_SEQ + lane];
    #pragma unroll
    for (int is = 0; is < 2; ++is) {
      int o = (is*4 + w)*1024 + lane*16;
      int row = o >> 7, c16 = (o >> 4) & 7;
      gload_lds16(Kh + hb + (size_t)row*64 + (c16 ^ (row & 7))*8,
                  (char*)Kl[0] + (is*4 + w)*1024);
    }
    #pragma unroll
    for (int j = 0; j < 8; ++j) {
      int da = vs_d0 + j, db = vs_d0 + 8 + j;
      *(u16*)((char*)VT[0] + da*128 + ((2*vs_s) ^ ((da & 7) << 4))) = (u16)vreg0[j];
      *(u16*)((char*)VT[0] + db*128 + ((2*vs_s) ^ ((db & 7) << 4))) = (u16)vreg1[j];
    }
    asm volatile("s_waitcnt vmcnt(0) lgkmcnt(0)" ::: "memory");
    __builtin_amdgcn_s_barrier();
  }
  int kpmv_cur = kpmreg;

  for (int t = 0; t < nt; ++t) {
    const int curb = t & 1, nxtb = curb ^ 1;
    const int s0 = t * 64;
    const bool haveNext = (t + 1 < nt);

    // 1. prefetch tile t+1 (V->regs first, then kpm, then K->LDS; oldest-first order)
    if (haveNext) {
      const int sn = s0 + 64;
      const u16* vp = Vh + hb + (size_t)(sn + vs_s)*64 + vs_d0;
      vreg0 = *(const bf16x8*)vp;
      vreg1 = *(const bf16x8*)(vp + 8);
      kpmreg = kpm[b*T_SEQ + sn + lane];
      #pragma unroll
      for (int is = 0; is < 2; ++is) {
        int o = (is*4 + w)*1024 + lane*16;
        int row = o >> 7, c16 = (o >> 4) & 7;
        gload_lds16(Kh + hb + (size_t)(sn + row)*64 + (c16 ^ (row & 7))*8,
                    (char*)Kl[nxtb] + (is*4 + w)*1024);
      }
    }

    // 2. S = Q K^T
    f32x4 sacc[2][4];
    #pragma unroll
    for (int mf = 0; mf < 2; ++mf)
      #pragma unroll
      for (int nf = 0; nf < 4; ++nf) sacc[mf][nf] = (f32x4){0.f,0.f,0.f,0.f};
    {
      bf16x8 kf[4][2];
      #pragma unroll
      for (int nf = 0; nf < 4; ++nf)
        #pragma unroll
        for (int kc = 0; kc < 2; ++kc) {
          int row = nf*16 + c;
          int colb = kc*64 + g*16;
          kf[nf][kc] = *(const bf16x8*)((const char*)Kl[curb] + row*128 + (colb ^ ((row & 7) << 4)));
        }
      __builtin_amdgcn_s_setprio(1);
      #pragma unroll
      for (int mf = 0; mf < 2; ++mf)
        #pragma unroll
        for (int nf = 0; nf < 4; ++nf)
          #pragma unroll
          for (int kc = 0; kc < 2; ++kc)
            sacc[mf][nf] = __builtin_amdgcn_mfma_f32_16x16x32_bf16(
                qf[mf][kc], kf[nf][kc], sacc[mf][nf], 0, 0, 0);
      __builtin_amdgcn_s_setprio(0);
    }

    int pmv[4];
    #pragma unroll
    for (int nf = 0; nf < 4; ++nf) pmv[nf] = __shfl(kpmv_cur, nf*16 + c, 64);

    // 3. online softmax, P -> per-wave LDS
    #pragma unroll
    for (int mf = 0; mf < 2; ++mf) {
      const int qb = q0 + w*32 + mf*16 + g*4;
      float sv[4][4];
      #pragma unroll
      for (int nf = 0; nf < 4; ++nf) {
        const int kv = s0 + nf*16 + c;
        #pragma unroll
        for (int r = 0; r < 4; ++r) {
          float x = sacc[mf][nf][r];
          sv[nf][r] = ((kv > qb + r) || pmv[nf]) ? -__builtin_inff() : x;
        }
      }
      #pragma unroll
      for (int r = 0; r < 4; ++r) {
        float rm = fmaxf(fmaxf(sv[0][r], sv[1][r]), fmaxf(sv[2][r], sv[3][r]));
        #pragma unroll
        for (int off = 1; off < 16; off <<= 1) rm = fmaxf(rm, __shfl_xor(rm, off, 64));
        const float mo = mrow[mf][r];
        const float mn = fmaxf(mo, rm);
        const bool deadrow = (mn == -__builtin_inff());
        const float sc = deadrow ? 1.0f : __expf(mo - mn);
        mrow[mf][r] = mn;
        float ps = 0.f;
        u16 pb[4];
        #pragma unroll
        for (int nf = 0; nf < 4; ++nf) {
          float p = deadrow ? 0.f : __expf(sv[nf][r] - mn);
          ps += p;
          pb[nf] = f2bf(p);
        }
        #pragma unroll
        for (int off = 1; off < 16; off <<= 1) ps += __shfl_xor(ps, off, 64);
        lrow[mf][r] = lrow[mf][r] * sc + ps;
        #pragma unroll
        for (int dt = 0; dt < 4; ++dt) cacc[mf][dt][r] *= sc;
        const int prow = mf*16 + g*4 + r;
        #pragma unroll
        for (int nf = 0; nf < 4; ++nf)
          *(u16*)((char*)Pl[w] + prow*128 + ((nf*32 + 2*c) ^ ((prow & 7) << 4))) = pb[nf];
      }
    }

    // 4. ctx += P V
    {
      bf16x8 pf[2][2], vf2[4][2];
      #pragma unroll
      for (int mf = 0; mf < 2; ++mf)
        #pragma unroll
        for (int sc2 = 0; sc2 < 2; ++sc2) {
          int row = mf*16 + c;
          int colb = sc2*64 + g*16;
          pf[mf][sc2] = *(const bf16x8*)((const char*)Pl[w] + row*128 + (colb ^ ((row & 7) << 4)));
        }
      #pragma unroll
      for (int dt = 0; dt < 4; ++dt)
        #pragma unroll
        for (int sc2 = 0; sc2 < 2; ++sc2) {
          int row = dt*16 + c;
          int colb = sc2*64 + g*16;
          vf2[dt][sc2] = *(const bf16x8*)((const char*)VT[curb] + row*128 + (colb ^ ((row & 7) << 4)));
        }
      __builtin_amdgcn_s_setprio(1);
      #pragma unroll
      for (int mf = 0; mf < 2; ++mf)
        #pragma unroll
        for (int dt = 0; dt < 4; ++dt)
          #pragma unroll
          for (int sc2 = 0; sc2 < 2; ++sc2)
            cacc[mf][dt] = __builtin_amdgcn_mfma_f32_16x16x32_bf16(
                pf[mf][sc2], vf2[dt][sc2], cacc[mf][dt], 0, 0, 0);
      __builtin_amdgcn_s_setprio(0);
    }

    // 5. write next V tile + kpm, drain, single barrier
    if (haveNext) {
      #pragma unroll
      for (int j = 0; j < 8; ++j) {
        int da = vs_d0 + j, db = vs_d0 + 8 + j;
        *(u16*)((char*)VT[nxtb] + da*128 + ((2*vs_s) ^ ((da & 7) << 4))) = (u16)vreg0[j];
        *(u16*)((char*)VT[nxtb] + db*128 + ((2*vs_s) ^ ((db & 7) << 4))) = (u16)vreg1[j];
      }
      kpmv_cur = kpmreg;
      asm volatile("s_waitcnt vmcnt(0) lgkmcnt(0)" ::: "memory");
      __builtin_amdgcn_s_barrier();
    }
  }

  // epilogue
  #pragma unroll
  for (int mf = 0; mf < 2; ++mf)
    #pragma unroll
    for (int r = 0; r < 4; ++r) {
      const int q = q0 + w*32 + mf*16 + g*4 + r;
      const float l = lrow[mf][r];
      const bool dead = (l == 0.f);
      const float rl = dead ? 0.f : 1.0f / l;
      #pragma unroll
      for (int dt = 0; dt < 4; ++dt) {
        const int d = dt*16 + c;
        float v = dead ? vsum[bh*64 + d] * (1.0f/2048.0f) : cacc[mf][dt][r] * rl;
        ctx2[(size_t)(q*2 + b)*1024 + (size_t)h*64 + d] = f2bf(v);
      }
    }
}

extern "C" void kernel_launch(void* const* d_in, const int* in_sizes, int n_in,
                              void* d_out, int out_size, void* d_ws, size_t ws_size,
                              hipStream_t stream) {
  const float* query = (const float*)d_in[0];
  const int*   kpm   = (const int*)d_in[1];
  const float* Wq = (const float*)d_in[3];
  const float* bq = (const float*)d_in[4];
  const float* Wk = (const float*)d_in[5];
  const float* bk = (const float*)d_in[6];
  const float* Wv = (const float*)d_in[7];
  const float* bv = (const float*)d_in[8];
  const float* Wo = (const float*)d_in[9];
  const float* bo = (const float*)d_in[10];

  char* ws = (char*)d_ws;
  u16*   qbf  = (u16*)(ws);
  u16*   wbf  = (u16*)(ws + 8388608);
  u16*   qkvh = (u16*)(ws + 16777216);
  u16*   ctx2 = (u16*)(ws + 41943040);
  float* vsum = (float*)(ws + 50331648);

  cvt_kernel<<<dim3(4096), 256, 0, stream>>>(query, qbf, 4194304);
  cvt4_kernel<<<dim3(1024, 4), 256, 0, stream>>>(Wq, Wk, Wv, Wo, wbf);

  hipMemsetAsync(vsum, 0, 2048 * sizeof(float), stream);

  gemm_qkv<<<dim3(32, 16, 3), 256, 0, stream>>>(qbf, wbf, bq, bk, bv, qkvh);
  vsum_kernel<<<dim3(256), 256, 0, stream>>>(qkvh + 2*4194304, vsum);
  flash_attn<<<dim3(512), 256, 0, stream>>>(qkvh, qkvh + 1*4194304,
                                            qkvh + 2*4194304, kpm, vsum, ctx2);
  gemm_out<<<dim3(32, 16), 256, 0, stream>>>(ctx2, wbf + 3*1048576, bo, (float*)d_out);
}

// Round 4
// 151.070 us; speedup vs baseline: 2.1262x; 1.1555x over previous
//
#include <hip/hip_runtime.h>
#include <hip/hip_bf16.h>
#include <stdint.h>

typedef unsigned short u16;
typedef uint32_t u32;
typedef unsigned long long u64;
typedef __attribute__((ext_vector_type(8))) short bf16x8;
typedef __attribute__((ext_vector_type(4))) float f32x4;
typedef __attribute__((ext_vector_type(16))) float f32x16;
typedef __attribute__((ext_vector_type(4))) u32 u32x4;

#define T_SEQ 2048

__device__ __forceinline__ float bf2f(u16 u) {
  union { u32 i; float f; } v; v.i = ((u32)u) << 16; return v.f;
}
__device__ __forceinline__ u16 f2bf(float f) {
  union { float f; u32 i; } v; v.f = f;
  u32 u = v.i;
  return (u16)((u + 0x7fffu + ((u >> 16) & 1u)) >> 16);
}
__device__ __forceinline__ u32 pack2bf(float lo, float hi) {
  return (u32)f2bf(lo) | ((u32)f2bf(hi) << 16);
}

__device__ __forceinline__ void gload_lds16(const void* g, void* l) {
  __builtin_amdgcn_global_load_lds(
      (const __attribute__((address_space(1))) void*)g,
      (__attribute__((address_space(3))) void*)l, 16, 0, 0);
}

// ---------------- fp32 -> bf16 converts ----------------
__global__ __launch_bounds__(256) void cvt_kernel(const float* __restrict__ src,
                                                  u16* __restrict__ dst, int n) {
  int i = (blockIdx.x * 256 + threadIdx.x) * 4;
  if (i + 3 < n) {
    const float4 v = *(const float4*)(src + i);
    ushort4 o;
    o.x = f2bf(v.x); o.y = f2bf(v.y); o.z = f2bf(v.z); o.w = f2bf(v.w);
    *(ushort4*)(dst + i) = o;
  }
}

__global__ __launch_bounds__(256) void cvt4_kernel(
    const float* __restrict__ s0, const float* __restrict__ s1,
    const float* __restrict__ s2, const float* __restrict__ s3,
    u16* __restrict__ dst) {
  const int z = blockIdx.y;
  const float* src = (z == 0) ? s0 : (z == 1) ? s1 : (z == 2) ? s2 : s3;
  int i = (blockIdx.x * 256 + threadIdx.x) * 4;
  const float4 v = *(const float4*)(src + i);
  ushort4 o;
  o.x = f2bf(v.x); o.y = f2bf(v.y); o.z = f2bf(v.z); o.w = f2bf(v.w);
  *(ushort4*)(dst + (size_t)z * 1048576 + i) = o;
}

// ---------------- GEMM core: C[128x64] += A[128xK] * B[64xK]^T, K=1024 ----
// (verified passing in R1/R2)
__device__ __forceinline__ void gemm_core_128x64(
    f32x4 acc[2][4], const u16* __restrict__ A, const u16* __restrict__ Bw,
    int bm, int bn, u16* As, u16* Bs)
{
  const int tid = threadIdx.x;
  const int w = tid >> 6, lane = tid & 63, g = lane >> 4, c = lane & 15;
  for (int k0 = 0; k0 < 1024; k0 += 64) {
    __syncthreads();
    #pragma unroll
    for (int is = 0; is < 4; ++is) {
      int o = (is*4 + w)*1024 + lane*16;
      int row = o >> 7, c16 = (o >> 4) & 7;
      gload_lds16(A + (size_t)(bm*128 + row)*1024 + k0 + (c16 ^ (row & 7))*8,
                  (char*)As + (is*4 + w)*1024);
    }
    #pragma unroll
    for (int is = 0; is < 2; ++is) {
      int o = (is*4 + w)*1024 + lane*16;
      int row = o >> 7, c16 = (o >> 4) & 7;
      gload_lds16(Bw + (size_t)(bn*64 + row)*1024 + k0 + (c16 ^ (row & 7))*8,
                  (char*)Bs + (is*4 + w)*1024);
    }
    __syncthreads();
    bf16x8 af[2][2], bfr[4][2];
    #pragma unroll
    for (int mf = 0; mf < 2; ++mf)
      #pragma unroll
      for (int kc = 0; kc < 2; ++kc) {
        int row = w*32 + mf*16 + c;
        int colb = kc*64 + g*16;
        af[mf][kc] = *(const bf16x8*)((const char*)As + row*128 + (colb ^ ((row & 7) << 4)));
      }
    #pragma unroll
    for (int nf = 0; nf < 4; ++nf)
      #pragma unroll
      for (int kc = 0; kc < 2; ++kc) {
        int row = nf*16 + c;
        int colb = kc*64 + g*16;
        bfr[nf][kc] = *(const bf16x8*)((const char*)Bs + row*128 + (colb ^ ((row & 7) << 4)));
      }
    #pragma unroll
    for (int mf = 0; mf < 2; ++mf)
      #pragma unroll
      for (int nf = 0; nf < 4; ++nf)
        #pragma unroll
        for (int kc = 0; kc < 2; ++kc)
          acc[mf][nf] = __builtin_amdgcn_mfma_f32_16x16x32_bf16(
              af[mf][kc], bfr[nf][kc], acc[mf][nf], 0, 0, 0);
  }
}

// ---------------- QKV projection ----------------
__global__ __launch_bounds__(256, 2) void gemm_qkv(
    const u16* __restrict__ Abf, const u16* __restrict__ Wbf,
    const float* __restrict__ bq, const float* __restrict__ bk,
    const float* __restrict__ bv, u16* __restrict__ qkvh)
{
  __shared__ __align__(16) u16 As[128*64];
  __shared__ __align__(16) u16 Bs[64*64];
  f32x4 acc[2][4];
  #pragma unroll
  for (int mf = 0; mf < 2; ++mf)
    #pragma unroll
    for (int nf = 0; nf < 4; ++nf) acc[mf][nf] = (f32x4){0.f,0.f,0.f,0.f};
  const int z = blockIdx.z;
  gemm_core_128x64(acc, Abf, Wbf + (size_t)z*1048576, blockIdx.x, blockIdx.y, As, Bs);
  const float* bias = (z == 0) ? bq : (z == 1) ? bk : bv;
  const float scl = (z == 0) ? 0.125f : 1.0f;
  u16* dst = qkvh + (size_t)z * 4194304;
  const int tid = threadIdx.x, w = tid >> 6, lane = tid & 63, g = lane >> 4, c = lane & 15;
  #pragma unroll
  for (int mf = 0; mf < 2; ++mf)
    #pragma unroll
    for (int nf = 0; nf < 4; ++nf) {
      int col = blockIdx.y*64 + nf*16 + c;
      float bcol = bias[col];
      int h = col >> 6, d = col & 63;
      #pragma unroll
      for (int r = 0; r < 4; ++r) {
        int row = blockIdx.x*128 + w*32 + mf*16 + g*4 + r;
        int t = row >> 1, bb = row & 1;
        float v = (acc[mf][nf][r] + bcol) * scl;
        dst[(size_t)(bb*16 + h)*131072 + (size_t)t*64 + d] = f2bf(v);
      }
    }
}

// ---------------- output projection ----------------
__global__ __launch_bounds__(256, 2) void gemm_out(
    const u16* __restrict__ ctx2, const u16* __restrict__ Wobf,
    const float* __restrict__ bo, float* __restrict__ out)
{
  __shared__ __align__(16) u16 As[128*64];
  __shared__ __align__(16) u16 Bs[64*64];
  f32x4 acc[2][4];
  #pragma unroll
  for (int mf = 0; mf < 2; ++mf)
    #pragma unroll
    for (int nf = 0; nf < 4; ++nf) acc[mf][nf] = (f32x4){0.f,0.f,0.f,0.f};
  gemm_core_128x64(acc, ctx2, Wobf, blockIdx.x, blockIdx.y, As, Bs);
  const int tid = threadIdx.x, w = tid >> 6, lane = tid & 63, g = lane >> 4, c = lane & 15;
  #pragma unroll
  for (int mf = 0; mf < 2; ++mf)
    #pragma unroll
    for (int nf = 0; nf < 4; ++nf) {
      int col = blockIdx.y*64 + nf*16 + c;
      float bcol = bo[col];
      #pragma unroll
      for (int r = 0; r < 4; ++r) {
        int row = blockIdx.x*128 + w*32 + mf*16 + g*4 + r;
        out[(size_t)row*1024 + col] = acc[mf][nf][r] + bcol;
      }
    }
}

// ---------------- V transpose + column sums ----------------
// V[bh][t][64] -> Vt[bh][d][2048]; vsum[bh][d] += partial (vs pre-zeroed).
// grid 1024 = 32 bh x 32 t-chunks(64), 256 threads.
__global__ __launch_bounds__(256) void vtrans_kernel(const u16* __restrict__ Vh,
                                                     u16* __restrict__ Vt,
                                                     float* __restrict__ vs) {
  __shared__ u16 tile[64][72];
  const int bh = blockIdx.x >> 5, tc = blockIdx.x & 31;
  const int t0 = tc * 64;
  const int tid = threadIdx.x;
  {
    const int tl = tid >> 2, d0 = (tid & 3) * 16;
    const u16* src = Vh + (size_t)bh*131072 + (size_t)(t0 + tl)*64 + d0;
    bf16x8 a = *(const bf16x8*)src;
    bf16x8 b2 = *(const bf16x8*)(src + 8);
    #pragma unroll
    for (int j = 0; j < 8; ++j) {
      tile[d0 + j][tl] = (u16)a[j];
      tile[d0 + 8 + j][tl] = (u16)b2[j];
    }
  }
  __syncthreads();
  {
    const int d = tid >> 2, tq = (tid & 3) * 16;
    bf16x8 o0, o1;
    float s = 0.f;
    #pragma unroll
    for (int j = 0; j < 8; ++j) {
      u16 x0 = tile[d][tq + j], x1 = tile[d][tq + 8 + j];
      o0[j] = (short)x0; o1[j] = (short)x1;
      s += bf2f(x0) + bf2f(x1);
    }
    u16* dst = Vt + (size_t)bh*131072 + (size_t)d*2048 + t0 + tq;
    *(bf16x8*)dst = o0;
    *(bf16x8*)(dst + 8) = o1;
    s += __shfl_xor(s, 1, 64);
    s += __shfl_xor(s, 2, 64);
    if ((tid & 3) == 0) atomicAdd(&vs[bh*64 + d], s);
  }
}

// ---------------- flash attention: 1-wave blocks, swapped 32x32 MFMA -------
// grid 2048 = 32 bh x 64 q-tiles(32 rows). No LDS, no barriers, no asm.
// S^T = mfma(K, Q): lane owns q = lane&31; softmax per-lane + one shfl_xor(32).
// P packed to bf16 in-register (manual pack), exchanged via shfl_xor(32).
// PV: ctx^T = mfma(V^T, P) with V^T fragments loaded directly from Vt global.
#define ZERO16 (f32x16){0.f,0.f,0.f,0.f,0.f,0.f,0.f,0.f,0.f,0.f,0.f,0.f,0.f,0.f,0.f,0.f}
#define NEGINF (-__builtin_inff())

__global__ __launch_bounds__(64, 2) void flash_attn(
    const u16* __restrict__ Qh, const u16* __restrict__ Kh,
    const u16* __restrict__ Vt, const int* __restrict__ kpm,
    const float* __restrict__ vsum, u16* __restrict__ ctx2)
{
  const int lane = threadIdx.x;
  const int l31 = lane & 31, hi = lane >> 5;

  // id -> (bh, qt): id&7 = XCD (round-robin dispatch) so each XCD owns 4 bh;
  // qt reversal pairs light/heavy tiles for CU load balance.
  const int id = blockIdx.x;
  const int xcd = id & 7, rest = id >> 3;
  const int bh = xcd * 4 + (rest & 3);
  const int pr = rest >> 2;
  const int p = pr & 7, kk = pr >> 3;
  const int qp = p*4 + (kk >> 1);
  const int qt = (kk & 1) ? (63 - qp) : qp;
  const int b = bh >> 4, h = bh & 15;
  const int q0 = qt * 32;
  const size_t hbase = (size_t)bh * 131072;
  const int nt = (q0 >> 6) + 1;
  const int q = q0 + l31;

  // Q fragments (B-operand): lane holds Q[q][k = kt*16 + hi*8 + j]
  bf16x8 qfrag[4];
  #pragma unroll
  for (int kt = 0; kt < 4; ++kt)
    qfrag[kt] = *(const bf16x8*)(Qh + hbase + (size_t)q*64 + kt*16 + hi*8);

  // K fragments (A-operand): lane holds K[sub*32 + l31][kt*16 + hi*8 + j]
  bf16x8 kreg[2][4];
  #pragma unroll
  for (int sub = 0; sub < 2; ++sub)
    #pragma unroll
    for (int kt = 0; kt < 4; ++kt)
      kreg[sub][kt] = *(const bf16x8*)(Kh + hbase + (size_t)(sub*32 + l31)*64 + kt*16 + hi*8);

  int kpmv_cur = kpm[b*T_SEQ + lane];
  int kpmv_nxt = 0;

  float mrow = NEGINF, lrow = 0.f;
  f32x16 cacc0 = ZERO16, cacc1 = ZERO16;

  for (int t = 0; t < nt; ++t) {
    const int s0 = t * 64;
    const bool notLast = (t + 1 < nt);

    // V^T fragments for THIS tile (A-operand): Vt[db*32 + l31][s0 + ks*16 + hi*8 + j]
    bf16x8 vf[2][4];
    #pragma unroll
    for (int db = 0; db < 2; ++db)
      #pragma unroll
      for (int ks = 0; ks < 4; ++ks)
        vf[db][ks] = *(const bf16x8*)(Vt + hbase + (size_t)(db*32 + l31)*2048 + s0 + ks*16 + hi*8);

    // S^T = K Q^T : lane owns q = l31; reg i: kv = s0 + sub*32 + (i&3) + 8*(i>>2) + 4*hi
    f32x16 st0 = ZERO16, st1 = ZERO16;
    __builtin_amdgcn_s_setprio(1);
    #pragma unroll
    for (int kt = 0; kt < 4; ++kt) {
      st0 = __builtin_amdgcn_mfma_f32_32x32x16_bf16(kreg[0][kt], qfrag[kt], st0, 0, 0, 0);
      st1 = __builtin_amdgcn_mfma_f32_32x32x16_bf16(kreg[1][kt], qfrag[kt], st1, 0, 0, 0);
    }
    __builtin_amdgcn_s_setprio(0);

    // prefetch K(t+1) + kpm(t+1); softmax below hides the latency
    if (notLast) {
      #pragma unroll
      for (int sub = 0; sub < 2; ++sub)
        #pragma unroll
        for (int kt = 0; kt < 4; ++kt)
          kreg[sub][kt] = *(const bf16x8*)(Kh + hbase + (size_t)(s0 + 64 + sub*32 + l31)*64 + kt*16 + hi*8);
      kpmv_nxt = kpm[b*T_SEQ + s0 + 64 + lane];
    }

    // mask + online softmax (per-lane; one cross-lane swap for the 64-row halves)
    {
      const u64 mask = __ballot(kpmv_cur != 0);   // bit i = kv s0+i padded
      const u32 m0 = (u32)mask, m1 = (u32)(mask >> 32);
      const u64 m4 = mask >> 4;
      const u32 m4l = (u32)m4, m4h = (u32)(m4 >> 32);
      const u32 w0 = hi ? m4l : m0;
      const u32 w1 = hi ? m4h : m1;
      const int lim = q - s0 - 4*hi;
      #pragma unroll
      for (int m = 0; m < 4; ++m) {
        u32 nib0 = (w0 >> (m*8)) & 15u;
        u32 nib1 = (w1 >> (m*8)) & 15u;
        if (!notLast) {   // causal kill only possible in the last tile
          int t0c = lim - m*8;       int c0 = min(max(t0c + 1, 0), 4);
          int t1c = lim - 32 - m*8;  int c1 = min(max(t1c + 1, 0), 4);
          nib0 |= (0xFu << c0) & 0xFu;
          nib1 |= (0xFu << c1) & 0xFu;
        }
        #pragma unroll
        for (int r = 0; r < 4; ++r) {
          if ((nib0 >> r) & 1) st0[m*4 + r] = NEGINF;
          if ((nib1 >> r) & 1) st1[m*4 + r] = NEGINF;
        }
      }
      float rm = st0[0];
      #pragma unroll
      for (int i = 1; i < 16; ++i) rm = fmaxf(rm, st0[i]);
      #pragma unroll
      for (int i = 0; i < 16; ++i) rm = fmaxf(rm, st1[i]);
      rm = fmaxf(rm, __shfl_xor(rm, 32, 64));
      const float mn = fmaxf(mrow, rm);
      const bool dead = (mn == NEGINF);
      const float sc = dead ? 1.f : __expf(mrow - mn);
      mrow = mn;
      float ps = 0.f;
      #pragma unroll
      for (int i = 0; i < 16; ++i) {
        float pv = dead ? 0.f : __expf(st0[i] - mn);
        st0[i] = pv; ps += pv;
      }
      #pragma unroll
      for (int i = 0; i < 16; ++i) {
        float pv = dead ? 0.f : __expf(st1[i] - mn);
        st1[i] = pv; ps += pv;
      }
      ps += __shfl_xor(ps, 32, 64);
      lrow = lrow * sc + ps;
      #pragma unroll
      for (int i = 0; i < 16; ++i) { cacc0[i] *= sc; cacc1[i] *= sc; }
    }

    // pack P to bf16 pairs: pk[m2][w] covers kv = m2*8 + 4*hi + 2w + {0,1}
    u32 pk[8][2];
    #pragma unroll
    for (int m = 0; m < 4; ++m) {
      pk[m][0]   = pack2bf(st0[m*4+0], st0[m*4+1]);
      pk[m][1]   = pack2bf(st0[m*4+2], st0[m*4+3]);
      pk[4+m][0] = pack2bf(st1[m*4+0], st1[m*4+1]);
      pk[4+m][1] = pack2bf(st1[m*4+2], st1[m*4+3]);
    }
    // B-operand frags: pf[ks][j] = P[q][kv = ks*16 + hi*8 + j], exchange via shfl_xor(32)
    bf16x8 pf[4];
    #pragma unroll
    for (int ks = 0; ks < 4; ++ks) {
      u32 own0 = pk[2*ks][0],   own1 = pk[2*ks][1];
      u32 oth0 = pk[2*ks+1][0], oth1 = pk[2*ks+1][1];
      u32 r0 = __shfl_xor(hi ? own0 : oth0, 32, 64);
      u32 r1 = __shfl_xor(hi ? own1 : oth1, 32, 64);
      u32 w0 = hi ? r0 : own0;
      u32 w1 = hi ? r1 : own1;
      u32 w2 = hi ? oth0 : r0;
      u32 w3 = hi ? oth1 : r1;
      u32x4 wv = {w0, w1, w2, w3};
      pf[ks] = __builtin_bit_cast(bf16x8, wv);
    }

    // PV: ctx^T += V^T P^T
    __builtin_amdgcn_s_setprio(1);
    #pragma unroll
    for (int ks = 0; ks < 4; ++ks)
      cacc0 = __builtin_amdgcn_mfma_f32_32x32x16_bf16(vf[0][ks], pf[ks], cacc0, 0, 0, 0);
    #pragma unroll
    for (int ks = 0; ks < 4; ++ks)
      cacc1 = __builtin_amdgcn_mfma_f32_32x32x16_bf16(vf[1][ks], pf[ks], cacc1, 0, 0, 0);
    __builtin_amdgcn_s_setprio(0);

    kpmv_cur = kpmv_nxt;
  }

  // epilogue: lane holds ctx^T[d = subd*32 + 4hi + 8m + r][q = l31]
  const bool dead = (lrow == 0.f);
  const float rl = dead ? 0.f : 1.f / lrow;
  #pragma unroll
  for (int subd = 0; subd < 2; ++subd) {
    #pragma unroll
    for (int m = 0; m < 4; ++m) {
      const int d0 = subd*32 + hi*4 + m*8;
      float v0 = (subd ? cacc1[m*4+0] : cacc0[m*4+0]) * rl;
      float v1 = (subd ? cacc1[m*4+1] : cacc0[m*4+1]) * rl;
      float v2 = (subd ? cacc1[m*4+2] : cacc0[m*4+2]) * rl;
      float v3 = (subd ? cacc1[m*4+3] : cacc0[m*4+3]) * rl;
      if (dead) {
        const float* vs = vsum + bh*64 + d0;
        v0 = vs[0] * (1.0f/2048.0f);
        v1 = vs[1] * (1.0f/2048.0f);
        v2 = vs[2] * (1.0f/2048.0f);
        v3 = vs[3] * (1.0f/2048.0f);
      }
      ushort4 o;
      o.x = f2bf(v0); o.y = f2bf(v1); o.z = f2bf(v2); o.w = f2bf(v3);
      *(ushort4*)(ctx2 + (size_t)(q*2 + b)*1024 + h*64 + d0) = o;
    }
  }
}

extern "C" void kernel_launch(void* const* d_in, const int* in_sizes, int n_in,
                              void* d_out, int out_size, void* d_ws, size_t ws_size,
                              hipStream_t stream) {
  const float* query = (const float*)d_in[0];
  const int*   kpm   = (const int*)d_in[1];
  const float* Wq = (const float*)d_in[3];
  const float* bq = (const float*)d_in[4];
  const float* Wk = (const float*)d_in[5];
  const float* bk = (const float*)d_in[6];
  const float* Wv = (const float*)d_in[7];
  const float* bv = (const float*)d_in[8];
  const float* Wo = (const float*)d_in[9];
  const float* bo = (const float*)d_in[10];

  char* ws = (char*)d_ws;
  u16*   qbf  = (u16*)(ws);                  // [0, 8M): query bf16 (consumed by gemm_qkv)
  u16*   Vt   = (u16*)(ws);                  // [0, 8M): V^T — aliases qbf, written AFTER gemm_qkv
  u16*   wbf  = (u16*)(ws + 8388608);        // [8M, 16M): weights bf16
  u16*   qkvh = (u16*)(ws + 16777216);       // [16M, 40M): Q,K,V head-major
  u16*   ctx2 = (u16*)(ws + 41943040);       // [40M, 48M): attn output [T*B][E]
  float* vsum = (float*)(ws + 50331648);     // 2048 floats

  cvt_kernel<<<dim3(4096), 256, 0, stream>>>(query, qbf, 4194304);
  cvt4_kernel<<<dim3(1024, 4), 256, 0, stream>>>(Wq, Wk, Wv, Wo, wbf);

  hipMemsetAsync(vsum, 0, 2048 * sizeof(float), stream);

  gemm_qkv<<<dim3(32, 16, 3), 256, 0, stream>>>(qbf, wbf, bq, bk, bv, qkvh);
  vtrans_kernel<<<dim3(1024), 256, 0, stream>>>(qkvh + 2*4194304, Vt, vsum);
  flash_attn<<<dim3(2048), 64, 0, stream>>>(qkvh, qkvh + 1*4194304,
                                            Vt, kpm, vsum, ctx2);
  gemm_out<<<dim3(32, 16), 256, 0, stream>>>(ctx2, wbf + 3*1048576, bo, (float*)d_out);
}